// Round 12
// baseline (346.969 us; speedup 1.0000x reference)
//
#include <hip/hip_runtime.h>

#define NN 400000
#define NE 400000

typedef __attribute__((ext_vector_type(4))) float f32x4;
typedef __attribute__((ext_vector_type(8))) short s16x8;
typedef unsigned short ushort_t;

__device__ __forceinline__ ushort_t f2bf(float f) {
    union { float f; unsigned int u; } c;
    c.f = f;
    unsigned int u = c.u;
    u = u + 0x7fffu + ((u >> 16) & 1u);
    return (ushort_t)(u >> 16);
}
__device__ __forceinline__ float bf2f(ushort_t v) {
    union { unsigned int u; float f; } c;
    c.u = ((unsigned int)v) << 16;
    return c.f;
}

// --- detect whether edge_index arrived as int64 (odd 32-bit words all zero) ---
__global__ void k_detect(const int* __restrict__ ei_raw, int* __restrict__ flag) {
    if (threadIdx.x == 0 && blockIdx.x == 0) {
        int is64 = 1;
        for (int i = 0; i < 64; i++)
            if (ei_raw[2 * i + 1] != 0) { is64 = 0; break; }
        flag[0] = is64;
    }
}

__global__ void k_cvt_idx(const int* __restrict__ ei_raw, const int* __restrict__ flag,
                          int* __restrict__ ei32) {
    const int i = blockIdx.x * 256 + threadIdx.x;
    const int f = flag[0];
    ei32[i] = f ? ei_raw[2 * i] : ei_raw[i];
}

// --- W [128,512] f32 -> bf16, plain row-major ---
__global__ void k_wcvt(const float* __restrict__ W, ushort_t* __restrict__ wbf) {
    const int i = blockIdx.x * 256 + threadIdx.x;
    wbf[i] = f2bf(W[i]);
}

// --- fused: per-node u,v scores + x -> bf16 conversion (unchanged) ---
__global__ void k_uv_cvt(const float* __restrict__ x, const float* __restrict__ att,
                         ushort_t* __restrict__ xbf, float* __restrict__ uv) {
    const int lane = threadIdx.x & 63;
    const int wid = threadIdx.x >> 6;
    const int g = lane & 15;
    const int ns = lane >> 4;

    float areg[8][8];
#pragma unroll
    for (int h = 0; h < 4; h++) {
        const f32x4 fa = *(const f32x4*)(att + h * 256 + g * 8);
        const f32x4 fb = *(const f32x4*)(att + h * 256 + g * 8 + 4);
        const f32x4 ba = *(const f32x4*)(att + h * 256 + 128 + g * 8);
        const f32x4 bb = *(const f32x4*)(att + h * 256 + 128 + g * 8 + 4);
#pragma unroll
        for (int m = 0; m < 4; m++) {
            areg[h][m] = fa[m];     areg[h][4 + m] = fb[m];
            areg[4 + h][m] = ba[m]; areg[4 + h][4 + m] = bb[m];
        }
    }

    for (int tile = blockIdx.x; tile < NN / 32; tile += gridDim.x) {
        const int nb = tile * 32 + wid * 8 + ns;
#pragma unroll
        for (int t = 0; t < 2; t++) {
            const int n = nb + t * 4;
            const f32x4 xa = *(const f32x4*)(x + (size_t)n * 128 + g * 8);
            const f32x4 xb = *(const f32x4*)(x + (size_t)n * 128 + g * 8 + 4);
            s16x8 pk;
#pragma unroll
            for (int m = 0; m < 4; m++) { pk[m] = (short)f2bf(xa[m]); pk[4 + m] = (short)f2bf(xb[m]); }
            *(s16x8*)(xbf + (size_t)n * 128 + g * 8) = pk;
            float r[8];
#pragma unroll
            for (int v = 0; v < 8; v++) {
                float s = 0.f;
#pragma unroll
                for (int m = 0; m < 4; m++) s += xa[m] * areg[v][m];
#pragma unroll
                for (int m = 0; m < 4; m++) s += xb[m] * areg[v][4 + m];
                r[v] = s;
            }
#pragma unroll
            for (int mask = 1; mask <= 4; mask <<= 1)
#pragma unroll
                for (int v = 0; v < 8; v++) r[v] += __shfl_xor(r[v], mask, 64);
            const int gv = g & 7;
            float s = r[0];
#pragma unroll
            for (int v = 1; v < 8; v++) s = (gv == v) ? r[v] : s;
            s += __shfl_xor(s, 8, 64);
            if (g < 8) uv[(size_t)n * 8 + g] = s;
        }
    }
}

// --- per-edge: leaky_relu -> head softmax -> p=exp(score), atomic denom ---
__global__ void k_edge(const int* __restrict__ ei, const float* __restrict__ uv,
                       float* __restrict__ p, float* __restrict__ denom) {
    const int e = blockIdx.x * 256 + threadIdx.x;
    if (e >= NE) return;
    const int row = ei[e];
    const int col = ei[NE + e];
    const f32x4 u = *(const f32x4*)(uv + (size_t)row * 8);
    const f32x4 v = *(const f32x4*)(uv + (size_t)col * 8 + 4);
    float s[4];
    float mx = -1e30f;
#pragma unroll
    for (int h = 0; h < 4; h++) {
        float t = u[h] + v[h];
        t = t > 0.f ? t : 0.01f * t;
        s[h] = t;
        mx = fmaxf(mx, t);
    }
    float ex[4], sum = 0.f;
#pragma unroll
    for (int h = 0; h < 4; h++) { ex[h] = __expf(s[h] - mx); sum += ex[h]; }
    const float inv = 1.f / sum;
    f32x4 pv;
#pragma unroll
    for (int h = 0; h < 4; h++) pv[h] = __expf(ex[h] * inv);
    *(f32x4*)(p + (size_t)e * 4) = pv;
#pragma unroll
    for (int h = 0; h < 4; h++) atomicAdd(denom + (size_t)row * 4 + h, pv[h]);
}

// --- alpha_t[h][e] = p[e,h] / denom[row[e],h]  (transposed planes, C-frag friendly) ---
__global__ void k_alpha(const int* __restrict__ ei, const float* __restrict__ p,
                        const float* __restrict__ denom, float* __restrict__ alpha_t) {
    const int e = blockIdx.x * 256 + threadIdx.x;
    if (e >= NE) return;
    const int row = ei[e];
    const f32x4 pv = *(const f32x4*)(p + (size_t)e * 4);
    const f32x4 dv = *(const f32x4*)(denom + (size_t)row * 4);
#pragma unroll
    for (int h = 0; h < 4; h++) alpha_t[(size_t)h * NE + e] = pv[h] / dv[h];
}

// --- persistent head-split GEMM, v9: v8 + direct C-layout alpha loads (no bpermute).
//     16 waves (1024 thr), grid=256. Bsm 128KB + Asm 2x16KB = 160KB exactly.
//     Tile = 64 edges, double-buffered A via global_load_lds, 1 barrier/tile.
//     Wave = 32 edges (eg2, eb2) x 16 cols (cg8). av[h][eb] loaded straight from
//     alpha_t planes in C-fragment layout (16B quarter-wave broadcast, L2-hot) —
//     removes 512 ds_bpermute/tile from the LDS pipe. ---
__global__ __launch_bounds__(1024, 4) void k_gemm(
    const ushort_t* __restrict__ xbf, const int* __restrict__ ei,
    const float* __restrict__ alpha_t, const ushort_t* __restrict__ wbf,
    const float* __restrict__ bias, float* __restrict__ out)
{
    __shared__ __align__(16) ushort_t Bsm[128 * 512];   // 128KB [icol][k], swz ((icol&15)<<4)
    __shared__ __align__(16) ushort_t Asm[2][64 * 128]; // 2x16KB [e][k],  swz ((e&15)<<4)

    const int tid = threadIdx.x;
    const int lane = tid & 63;
    const int w = tid >> 6;       // 0..15
    const int eg = w & 1;         // edge group: rows eg*32..+32
    const int cg = w >> 1;        // col group:  cols cg*16..+16

    // stage W once (r10-proven conflict-free map)
    {
        const int icol = tid & 127, seg = tid >> 7;
        const ushort_t* src = wbf + icol * 512 + seg * 64;
#pragma unroll
        for (int m = 0; m < 8; m++) {
            const s16x8 v = *(const s16x8*)(src + m * 8);
            const int byte = icol * 1024 + ((seg * 128 + m * 16) ^ ((icol & 15) << 4));
            *(s16x8*)((char*)Bsm + byte) = v;
        }
    }
    const int icol = cg * 16 + (lane & 15);
    const float bias_r = bias[icol];

    const f32x4 zero = {0.f, 0.f, 0.f, 0.f};
    const int ntiles = NE / 64;
    const int stride = gridDim.x;

    // async A stage: 1 global_load_lds per thread, source-side swizzle (r6-proven)
    auto STAGE = [&](int tt, int b) {
        const int rr = w * 4 + (lane >> 4);
        const int col = ei[NE + tt * 64 + rr];
        const int c = (lane & 15) ^ (rr & 15);
        const ushort_t* src = xbf + (size_t)col * 128 + c * 8;
        __builtin_amdgcn_global_load_lds(
            (const __attribute__((address_space(1))) unsigned int*)src,
            (__attribute__((address_space(3))) unsigned int*)((char*)Asm[b] + w * 1024),
            16, 0, 0);
    };

    int t = blockIdx.x;
    int cur = 0;
    if (t < ntiles) STAGE(t, 0);

#pragma unroll 1
    for (; t < ntiles; t += stride) {
        __syncthreads();   // drains STAGE(cur); prev tile's buf reads all done
        const int tn = t + stride;
        if (tn < ntiles) STAGE(tn, cur ^ 1);   // in flight under this tile's compute

        // A fragments: h-invariant, read once, held (32 VGPR)
        s16x8 af[2][4];
#pragma unroll
        for (int eb = 0; eb < 2; eb++) {
            const int rr = eg * 32 + eb * 16 + (lane & 15);
#pragma unroll
            for (int ks = 0; ks < 4; ks++) {
                const int byte = rr * 256 + ((ks * 64 + (lane >> 4) * 16) ^ ((rr & 15) << 4));
                af[eb][ks] = *(const s16x8*)((const char*)Asm[cur] + byte);
            }
        }

        f32x4 fin[2];
        fin[0] = zero; fin[1] = zero;

        const int ebase = t * 64 + eg * 32 + (lane >> 4) * 4;

#pragma unroll
        for (int h = 0; h < 4; h++) {
            s16x8 bfr[4];
#pragma unroll
            for (int ks = 0; ks < 4; ks++) {
                const int byte = icol * 1024 +
                    ((h * 256 + ks * 64 + (lane >> 4) * 16) ^ ((icol & 15) << 4));
                bfr[ks] = *(const s16x8*)((const char*)Bsm + byte);
            }
#pragma unroll
            for (int eb = 0; eb < 2; eb++) {
                f32x4 a = __builtin_amdgcn_mfma_f32_16x16x32_bf16(af[eb][0], bfr[0], zero, 0, 0, 0);
#pragma unroll
                for (int ks = 1; ks < 4; ks++)
                    a = __builtin_amdgcn_mfma_f32_16x16x32_bf16(af[eb][ks], bfr[ks], a, 0, 0, 0);
                // alpha in C-fragment layout directly from the h-plane (no shuffles)
                const f32x4 av = *(const f32x4*)(alpha_t + (size_t)h * NE + ebase + eb * 16);
                fin[eb] += av * a;
            }
        }
        // epilogue: + bias + residual
#pragma unroll
        for (int eb = 0; eb < 2; eb++) {
#pragma unroll
            for (int r = 0; r < 4; r++) {
                const int e = t * 64 + eg * 32 + eb * 16 + (lane >> 4) * 4 + r;
                const size_t off = (size_t)e * 128 + icol;
                out[off] = fin[eb][r] + bias_r + bf2f(xbf[off]);
            }
        }
        cur ^= 1;
    }
}

extern "C" void kernel_launch(void* const* d_in, const int* in_sizes, int n_in,
                              void* d_out, int out_size, void* d_ws, size_t ws_size,
                              hipStream_t stream) {
    const float* x      = (const float*)d_in[0];
    const int*   ei_raw = (const int*)d_in[1];
    const float* att    = (const float*)d_in[2];
    const float* W      = (const float*)d_in[3];
    const float* b      = (const float*)d_in[4];
    float* out = (float*)d_out;

    char* ws = (char*)d_ws;
    float*    uv      = (float*)(ws);                     // N*8 f32   = 12.8 MB
    float*    p       = (float*)(ws + 12800000);          // E*4 f32   =  6.4 MB
    float*    denom   = (float*)(ws + 19200000);          // N*4 f32   =  6.4 MB
    float*    alpha_t = (float*)(ws + 25600000);          // 4 planes  =  6.4 MB
    ushort_t* wbf     = (ushort_t*)(ws + 32000000);       // 128 KB
    int*      flag    = (int*)(ws + 32200000);            // 4 B
    int*      ei32    = (int*)(ws + 32200064);            // 3.2 MB
    ushort_t* xbf     = (ushort_t*)(ws + 35400192);       // N*128 bf16 = 102.4 MB

    hipMemsetAsync(denom, 0, (size_t)NN * 4 * sizeof(float), stream);
    k_detect<<<1, 64, 0, stream>>>(ei_raw, flag);
    k_cvt_idx<<<2 * NE / 256, 256, 0, stream>>>(ei_raw, flag, ei32);
    k_wcvt<<<256, 256, 0, stream>>>(W, wbf);
    k_uv_cvt<<<2048, 256, 0, stream>>>(x, att, xbf, uv);
    k_edge<<<(NE + 255) / 256, 256, 0, stream>>>(ei32, uv, p, denom);
    k_alpha<<<(NE + 255) / 256, 256, 0, stream>>>(ei32, p, denom, alpha_t);
    k_gemm<<<256, 1024, 0, stream>>>(xbf, ei32, alpha_t, wbf, b, out);
}

// Round 13
// 339.924 us; speedup vs baseline: 1.0207x; 1.0207x over previous
//
#include <hip/hip_runtime.h>

#define NN 400000
#define NE 400000

typedef __attribute__((ext_vector_type(4))) float f32x4;
typedef __attribute__((ext_vector_type(8))) short s16x8;
typedef unsigned short ushort_t;

__device__ __forceinline__ ushort_t f2bf(float f) {
    union { float f; unsigned int u; } c;
    c.f = f;
    unsigned int u = c.u;
    u = u + 0x7fffu + ((u >> 16) & 1u);
    return (ushort_t)(u >> 16);
}
__device__ __forceinline__ float bf2f(ushort_t v) {
    union { unsigned int u; float f; } c;
    c.u = ((unsigned int)v) << 16;
    return c.f;
}

// --- detect whether edge_index arrived as int64 (odd 32-bit words all zero) ---
__global__ void k_detect(const int* __restrict__ ei_raw, int* __restrict__ flag) {
    if (threadIdx.x == 0 && blockIdx.x == 0) {
        int is64 = 1;
        for (int i = 0; i < 64; i++)
            if (ei_raw[2 * i + 1] != 0) { is64 = 0; break; }
        flag[0] = is64;
    }
}

__global__ void k_cvt_idx(const int* __restrict__ ei_raw, const int* __restrict__ flag,
                          int* __restrict__ ei32) {
    const int i = blockIdx.x * 256 + threadIdx.x;
    const int f = flag[0];
    ei32[i] = f ? ei_raw[2 * i] : ei_raw[i];
}

// --- W [128,512] f32 -> bf16, plain row-major ---
__global__ void k_wcvt(const float* __restrict__ W, ushort_t* __restrict__ wbf) {
    const int i = blockIdx.x * 256 + threadIdx.x;
    wbf[i] = f2bf(W[i]);
}

// --- fused: per-node u,v scores + x -> bf16 conversion (unchanged) ---
__global__ void k_uv_cvt(const float* __restrict__ x, const float* __restrict__ att,
                         ushort_t* __restrict__ xbf, float* __restrict__ uv) {
    const int lane = threadIdx.x & 63;
    const int wid = threadIdx.x >> 6;
    const int g = lane & 15;
    const int ns = lane >> 4;

    float areg[8][8];
#pragma unroll
    for (int h = 0; h < 4; h++) {
        const f32x4 fa = *(const f32x4*)(att + h * 256 + g * 8);
        const f32x4 fb = *(const f32x4*)(att + h * 256 + g * 8 + 4);
        const f32x4 ba = *(const f32x4*)(att + h * 256 + 128 + g * 8);
        const f32x4 bb = *(const f32x4*)(att + h * 256 + 128 + g * 8 + 4);
#pragma unroll
        for (int m = 0; m < 4; m++) {
            areg[h][m] = fa[m];     areg[h][4 + m] = fb[m];
            areg[4 + h][m] = ba[m]; areg[4 + h][4 + m] = bb[m];
        }
    }

    for (int tile = blockIdx.x; tile < NN / 32; tile += gridDim.x) {
        const int nb = tile * 32 + wid * 8 + ns;
#pragma unroll
        for (int t = 0; t < 2; t++) {
            const int n = nb + t * 4;
            const f32x4 xa = *(const f32x4*)(x + (size_t)n * 128 + g * 8);
            const f32x4 xb = *(const f32x4*)(x + (size_t)n * 128 + g * 8 + 4);
            s16x8 pk;
#pragma unroll
            for (int m = 0; m < 4; m++) { pk[m] = (short)f2bf(xa[m]); pk[4 + m] = (short)f2bf(xb[m]); }
            *(s16x8*)(xbf + (size_t)n * 128 + g * 8) = pk;
            float r[8];
#pragma unroll
            for (int v = 0; v < 8; v++) {
                float s = 0.f;
#pragma unroll
                for (int m = 0; m < 4; m++) s += xa[m] * areg[v][m];
#pragma unroll
                for (int m = 0; m < 4; m++) s += xb[m] * areg[v][4 + m];
                r[v] = s;
            }
#pragma unroll
            for (int mask = 1; mask <= 4; mask <<= 1)
#pragma unroll
                for (int v = 0; v < 8; v++) r[v] += __shfl_xor(r[v], mask, 64);
            const int gv = g & 7;
            float s = r[0];
#pragma unroll
            for (int v = 1; v < 8; v++) s = (gv == v) ? r[v] : s;
            s += __shfl_xor(s, 8, 64);
            if (g < 8) uv[(size_t)n * 8 + g] = s;
        }
    }
}

// --- per-edge: leaky_relu -> head softmax -> p=exp(score), atomic denom ---
__global__ void k_edge(const int* __restrict__ ei, const float* __restrict__ uv,
                       float* __restrict__ p, float* __restrict__ denom) {
    const int e = blockIdx.x * 256 + threadIdx.x;
    if (e >= NE) return;
    const int row = ei[e];
    const int col = ei[NE + e];
    const f32x4 u = *(const f32x4*)(uv + (size_t)row * 8);
    const f32x4 v = *(const f32x4*)(uv + (size_t)col * 8 + 4);
    float s[4];
    float mx = -1e30f;
#pragma unroll
    for (int h = 0; h < 4; h++) {
        float t = u[h] + v[h];
        t = t > 0.f ? t : 0.01f * t;
        s[h] = t;
        mx = fmaxf(mx, t);
    }
    float ex[4], sum = 0.f;
#pragma unroll
    for (int h = 0; h < 4; h++) { ex[h] = __expf(s[h] - mx); sum += ex[h]; }
    const float inv = 1.f / sum;
    f32x4 pv;
#pragma unroll
    for (int h = 0; h < 4; h++) pv[h] = __expf(ex[h] * inv);
    *(f32x4*)(p + (size_t)e * 4) = pv;
#pragma unroll
    for (int h = 0; h < 4; h++) atomicAdd(denom + (size_t)row * 4 + h, pv[h]);
}

// --- alpha_t[h][e] = p[e,h] / denom[row[e],h]  (transposed planes, C-frag friendly) ---
__global__ void k_alpha(const int* __restrict__ ei, const float* __restrict__ p,
                        const float* __restrict__ denom, float* __restrict__ alpha_t) {
    const int e = blockIdx.x * 256 + threadIdx.x;
    if (e >= NE) return;
    const int row = ei[e];
    const f32x4 pv = *(const f32x4*)(p + (size_t)e * 4);
    const f32x4 dv = *(const f32x4*)(denom + (size_t)row * 4);
#pragma unroll
    for (int h = 0; h < 4; h++) alpha_t[(size_t)h * NE + e] = pv[h] / dv[h];
}

// --- persistent head-split GEMM, v10: v9 with ALL alpha loads hoisted to the top
//     of the tile (issued before the af ds_reads -> latency overlapped), pinned
//     with keep-alive asm (within-iteration liveness, the case where it works).
//     v9's mistake: av load written inside the h-loop -> 8 serialized vmcnt(0)
//     stalls/tile (189 µs, MfmaUtil 11%). ---
__global__ __launch_bounds__(1024, 4) void k_gemm(
    const ushort_t* __restrict__ xbf, const int* __restrict__ ei,
    const float* __restrict__ alpha_t, const ushort_t* __restrict__ wbf,
    const float* __restrict__ bias, float* __restrict__ out)
{
    __shared__ __align__(16) ushort_t Bsm[128 * 512];   // 128KB [icol][k], swz ((icol&15)<<4)
    __shared__ __align__(16) ushort_t Asm[2][64 * 128]; // 2x16KB [e][k],  swz ((e&15)<<4)

    const int tid = threadIdx.x;
    const int lane = tid & 63;
    const int w = tid >> 6;       // 0..15
    const int eg = w & 1;         // edge group: rows eg*32..+32
    const int cg = w >> 1;        // col group:  cols cg*16..+16

    // stage W once (r10-proven conflict-free map)
    {
        const int icol = tid & 127, seg = tid >> 7;
        const ushort_t* src = wbf + icol * 512 + seg * 64;
#pragma unroll
        for (int m = 0; m < 8; m++) {
            const s16x8 v = *(const s16x8*)(src + m * 8);
            const int byte = icol * 1024 + ((seg * 128 + m * 16) ^ ((icol & 15) << 4));
            *(s16x8*)((char*)Bsm + byte) = v;
        }
    }
    const int icol = cg * 16 + (lane & 15);
    const float bias_r = bias[icol];

    const f32x4 zero = {0.f, 0.f, 0.f, 0.f};
    const int ntiles = NE / 64;
    const int stride = gridDim.x;

    // async A stage: 1 global_load_lds per thread, source-side swizzle (r6-proven)
    auto STAGE = [&](int tt, int b) {
        const int rr = w * 4 + (lane >> 4);
        const int col = ei[NE + tt * 64 + rr];
        const int c = (lane & 15) ^ (rr & 15);
        const ushort_t* src = xbf + (size_t)col * 128 + c * 8;
        __builtin_amdgcn_global_load_lds(
            (const __attribute__((address_space(1))) unsigned int*)src,
            (__attribute__((address_space(3))) unsigned int*)((char*)Asm[b] + w * 1024),
            16, 0, 0);
    };

    int t = blockIdx.x;
    int cur = 0;
    if (t < ntiles) STAGE(t, 0);

#pragma unroll 1
    for (; t < ntiles; t += stride) {
        __syncthreads();   // drains STAGE(cur); prev tile's buf reads all done
        const int tn = t + stride;
        if (tn < ntiles) STAGE(tn, cur ^ 1);   // in flight under this tile's compute

        // alpha: ALL 8 C-layout vectors issued up front (overlap with ds_reads below)
        const int ebase = t * 64 + eg * 32 + (lane >> 4) * 4;
        f32x4 av[4][2];
#pragma unroll
        for (int h = 0; h < 4; h++)
#pragma unroll
            for (int eb = 0; eb < 2; eb++)
                av[h][eb] = *(const f32x4*)(alpha_t + (size_t)h * NE + ebase + eb * 16);
#pragma unroll
        for (int h = 0; h < 4; h++)
#pragma unroll
            for (int eb = 0; eb < 2; eb++)
                asm volatile("" : "+v"(av[h][eb]));   // pin issue point (within-iter)

        // A fragments: h-invariant, read once, held (32 VGPR)
        s16x8 af[2][4];
#pragma unroll
        for (int eb = 0; eb < 2; eb++) {
            const int rr = eg * 32 + eb * 16 + (lane & 15);
#pragma unroll
            for (int ks = 0; ks < 4; ks++) {
                const int byte = rr * 256 + ((ks * 64 + (lane >> 4) * 16) ^ ((rr & 15) << 4));
                af[eb][ks] = *(const s16x8*)((const char*)Asm[cur] + byte);
            }
        }

        f32x4 fin[2];
        fin[0] = zero; fin[1] = zero;

#pragma unroll
        for (int h = 0; h < 4; h++) {
            s16x8 bfr[4];
#pragma unroll
            for (int ks = 0; ks < 4; ks++) {
                const int byte = icol * 1024 +
                    ((h * 256 + ks * 64 + (lane >> 4) * 16) ^ ((icol & 15) << 4));
                bfr[ks] = *(const s16x8*)((const char*)Bsm + byte);
            }
#pragma unroll
            for (int eb = 0; eb < 2; eb++) {
                f32x4 a = __builtin_amdgcn_mfma_f32_16x16x32_bf16(af[eb][0], bfr[0], zero, 0, 0, 0);
#pragma unroll
                for (int ks = 1; ks < 4; ks++)
                    a = __builtin_amdgcn_mfma_f32_16x16x32_bf16(af[eb][ks], bfr[ks], a, 0, 0, 0);
                fin[eb] += av[h][eb] * a;
            }
        }
        // epilogue: + bias + residual
#pragma unroll
        for (int eb = 0; eb < 2; eb++) {
#pragma unroll
            for (int r = 0; r < 4; r++) {
                const int e = t * 64 + eg * 32 + eb * 16 + (lane >> 4) * 4 + r;
                const size_t off = (size_t)e * 128 + icol;
                out[off] = fin[eb][r] + bias_r + bf2f(xbf[off]);
            }
        }
        cur ^= 1;
    }
}

extern "C" void kernel_launch(void* const* d_in, const int* in_sizes, int n_in,
                              void* d_out, int out_size, void* d_ws, size_t ws_size,
                              hipStream_t stream) {
    const float* x      = (const float*)d_in[0];
    const int*   ei_raw = (const int*)d_in[1];
    const float* att    = (const float*)d_in[2];
    const float* W      = (const float*)d_in[3];
    const float* b      = (const float*)d_in[4];
    float* out = (float*)d_out;

    char* ws = (char*)d_ws;
    float*    uv      = (float*)(ws);                     // N*8 f32   = 12.8 MB
    float*    p       = (float*)(ws + 12800000);          // E*4 f32   =  6.4 MB
    float*    denom   = (float*)(ws + 19200000);          // N*4 f32   =  6.4 MB
    float*    alpha_t = (float*)(ws + 25600000);          // 4 planes  =  6.4 MB
    ushort_t* wbf     = (ushort_t*)(ws + 32000000);       // 128 KB
    int*      flag    = (int*)(ws + 32200000);            // 4 B
    int*      ei32    = (int*)(ws + 32200064);            // 3.2 MB
    ushort_t* xbf     = (ushort_t*)(ws + 35400192);       // N*128 bf16 = 102.4 MB

    hipMemsetAsync(denom, 0, (size_t)NN * 4 * sizeof(float), stream);
    k_detect<<<1, 64, 0, stream>>>(ei_raw, flag);
    k_cvt_idx<<<2 * NE / 256, 256, 0, stream>>>(ei_raw, flag, ei32);
    k_wcvt<<<256, 256, 0, stream>>>(W, wbf);
    k_uv_cvt<<<2048, 256, 0, stream>>>(x, att, xbf, uv);
    k_edge<<<(NE + 255) / 256, 256, 0, stream>>>(ei32, uv, p, denom);
    k_alpha<<<(NE + 255) / 256, 256, 0, stream>>>(ei32, p, denom, alpha_t);
    k_gemm<<<256, 1024, 0, stream>>>(xbf, ei32, alpha_t, wbf, b, out);
}

// Round 14
// 286.982 us; speedup vs baseline: 1.2090x; 1.1845x over previous
//
#include <hip/hip_runtime.h>

#define NN 400000
#define NE 400000

typedef __attribute__((ext_vector_type(4))) float f32x4;
typedef __attribute__((ext_vector_type(8))) short s16x8;
typedef unsigned short ushort_t;

__device__ __forceinline__ ushort_t f2bf(float f) {
    union { float f; unsigned int u; } c;
    c.f = f;
    unsigned int u = c.u;
    u = u + 0x7fffu + ((u >> 16) & 1u);
    return (ushort_t)(u >> 16);
}
__device__ __forceinline__ float bf2f(ushort_t v) {
    union { unsigned int u; float f; } c;
    c.u = ((unsigned int)v) << 16;
    return c.f;
}

// --- detect int64 edge_index: 64 PARALLEL lane loads + ballot (was: serial
//     1-lane loop of 64 dependent loads ≈ 12 µs of pure latency) ---
__global__ void k_detect(const int* __restrict__ ei_raw, int* __restrict__ flag) {
    const int l = threadIdx.x;              // 64 threads
    const int v = ei_raw[2 * l + 1];
    const unsigned long long b = __ballot(v != 0);
    if (l == 0) flag[0] = (b == 0ULL) ? 1 : 0;
}

__global__ void k_cvt_idx(const int* __restrict__ ei_raw, const int* __restrict__ flag,
                          int* __restrict__ ei32) {
    const int i = blockIdx.x * 256 + threadIdx.x;
    const int f = flag[0];
    ei32[i] = f ? ei_raw[2 * i] : ei_raw[i];
}

// --- W [128,512] f32 -> bf16, plain row-major ---
__global__ void k_wcvt(const float* __restrict__ W, ushort_t* __restrict__ wbf) {
    const int i = blockIdx.x * 256 + threadIdx.x;
    wbf[i] = f2bf(W[i]);
}

// --- fused: per-node u,v scores + x -> bf16 conversion (unchanged) ---
__global__ void k_uv_cvt(const float* __restrict__ x, const float* __restrict__ att,
                         ushort_t* __restrict__ xbf, float* __restrict__ uv) {
    const int lane = threadIdx.x & 63;
    const int wid = threadIdx.x >> 6;
    const int g = lane & 15;
    const int ns = lane >> 4;

    float areg[8][8];
#pragma unroll
    for (int h = 0; h < 4; h++) {
        const f32x4 fa = *(const f32x4*)(att + h * 256 + g * 8);
        const f32x4 fb = *(const f32x4*)(att + h * 256 + g * 8 + 4);
        const f32x4 ba = *(const f32x4*)(att + h * 256 + 128 + g * 8);
        const f32x4 bb = *(const f32x4*)(att + h * 256 + 128 + g * 8 + 4);
#pragma unroll
        for (int m = 0; m < 4; m++) {
            areg[h][m] = fa[m];     areg[h][4 + m] = fb[m];
            areg[4 + h][m] = ba[m]; areg[4 + h][4 + m] = bb[m];
        }
    }

    for (int tile = blockIdx.x; tile < NN / 32; tile += gridDim.x) {
        const int nb = tile * 32 + wid * 8 + ns;
#pragma unroll
        for (int t = 0; t < 2; t++) {
            const int n = nb + t * 4;
            const f32x4 xa = *(const f32x4*)(x + (size_t)n * 128 + g * 8);
            const f32x4 xb = *(const f32x4*)(x + (size_t)n * 128 + g * 8 + 4);
            s16x8 pk;
#pragma unroll
            for (int m = 0; m < 4; m++) { pk[m] = (short)f2bf(xa[m]); pk[4 + m] = (short)f2bf(xb[m]); }
            *(s16x8*)(xbf + (size_t)n * 128 + g * 8) = pk;
            float r[8];
#pragma unroll
            for (int v = 0; v < 8; v++) {
                float s = 0.f;
#pragma unroll
                for (int m = 0; m < 4; m++) s += xa[m] * areg[v][m];
#pragma unroll
                for (int m = 0; m < 4; m++) s += xb[m] * areg[v][4 + m];
                r[v] = s;
            }
#pragma unroll
            for (int mask = 1; mask <= 4; mask <<= 1)
#pragma unroll
                for (int v = 0; v < 8; v++) r[v] += __shfl_xor(r[v], mask, 64);
            const int gv = g & 7;
            float s = r[0];
#pragma unroll
            for (int v = 1; v < 8; v++) s = (gv == v) ? r[v] : s;
            s += __shfl_xor(s, 8, 64);
            if (g < 8) uv[(size_t)n * 8 + g] = s;
        }
    }
}

// --- per-edge: leaky_relu -> head softmax -> p=exp(score), atomic denom ---
__global__ void k_edge(const int* __restrict__ ei, const float* __restrict__ uv,
                       float* __restrict__ p, float* __restrict__ denom) {
    const int e = blockIdx.x * 256 + threadIdx.x;
    if (e >= NE) return;
    const int row = ei[e];
    const int col = ei[NE + e];
    const f32x4 u = *(const f32x4*)(uv + (size_t)row * 8);
    const f32x4 v = *(const f32x4*)(uv + (size_t)col * 8 + 4);
    float s[4];
    float mx = -1e30f;
#pragma unroll
    for (int h = 0; h < 4; h++) {
        float t = u[h] + v[h];
        t = t > 0.f ? t : 0.01f * t;
        s[h] = t;
        mx = fmaxf(mx, t);
    }
    float ex[4], sum = 0.f;
#pragma unroll
    for (int h = 0; h < 4; h++) { ex[h] = __expf(s[h] - mx); sum += ex[h]; }
    const float inv = 1.f / sum;
    f32x4 pv;
#pragma unroll
    for (int h = 0; h < 4; h++) pv[h] = __expf(ex[h] * inv);
    *(f32x4*)(p + (size_t)e * 4) = pv;
#pragma unroll
    for (int h = 0; h < 4; h++) atomicAdd(denom + (size_t)row * 4 + h, pv[h]);
}

// --- alpha4[e] = p[e,:] / denom[row[e],:]  (e-major f32x4, sequential for gemm) ---
__global__ void k_alpha(const int* __restrict__ ei, const float* __restrict__ p,
                        const float* __restrict__ denom, float* __restrict__ alpha4) {
    const int e = blockIdx.x * 256 + threadIdx.x;
    if (e >= NE) return;
    const int row = ei[e];
    const f32x4 pv = *(const f32x4*)(p + (size_t)e * 4);
    const f32x4 dv = *(const f32x4*)(denom + (size_t)row * 4);
    *(f32x4*)(alpha4 + (size_t)e * 4) = pv / dv;
}

// --- persistent head-split GEMM, v8 (EXACT revert — best measured: 120.6 µs).
//     16 waves, grid=256. Bsm 128KB + Asm 2x16KB = 160KB. Tile=64 edges,
//     double-buffered A via global_load_lds, 1 barrier/tile, per-lane alpha
//     load + bpermute shuffles (v9/v10 plane-load variants regressed: hipcc
//     sinks VMEM loads to first use -> serialized vmcnt stalls in the h-loop). ---
__global__ __launch_bounds__(1024, 4) void k_gemm(
    const ushort_t* __restrict__ xbf, const int* __restrict__ ei,
    const float* __restrict__ alpha4, const ushort_t* __restrict__ wbf,
    const float* __restrict__ bias, float* __restrict__ out)
{
    __shared__ __align__(16) ushort_t Bsm[128 * 512];   // 128KB [icol][k], swz ((icol&15)<<4)
    __shared__ __align__(16) ushort_t Asm[2][64 * 128]; // 2x16KB [e][k],  swz ((e&15)<<4)

    const int tid = threadIdx.x;
    const int lane = tid & 63;
    const int w = tid >> 6;       // 0..15
    const int eg = w & 1;         // edge group: rows eg*32..+32
    const int cg = w >> 1;        // col group:  cols cg*16..+16

    // stage W once (r10-proven conflict-free map)
    {
        const int icol = tid & 127, seg = tid >> 7;
        const ushort_t* src = wbf + icol * 512 + seg * 64;
#pragma unroll
        for (int m = 0; m < 8; m++) {
            const s16x8 v = *(const s16x8*)(src + m * 8);
            const int byte = icol * 1024 + ((seg * 128 + m * 16) ^ ((icol & 15) << 4));
            *(s16x8*)((char*)Bsm + byte) = v;
        }
    }
    const int icol = cg * 16 + (lane & 15);
    const float bias_r = bias[icol];

    const f32x4 zero = {0.f, 0.f, 0.f, 0.f};
    const int ntiles = NE / 64;
    const int stride = gridDim.x;

    // async A stage: 1 global_load_lds per thread, source-side swizzle (r6-proven)
    auto STAGE = [&](int tt, int b) {
        const int rr = w * 4 + (lane >> 4);
        const int col = ei[NE + tt * 64 + rr];
        const int c = (lane & 15) ^ (rr & 15);
        const ushort_t* src = xbf + (size_t)col * 128 + c * 8;
        __builtin_amdgcn_global_load_lds(
            (const __attribute__((address_space(1))) unsigned int*)src,
            (__attribute__((address_space(3))) unsigned int*)((char*)Asm[b] + w * 1024),
            16, 0, 0);
    };

    int t = blockIdx.x;
    int cur = 0;
    if (t < ntiles) STAGE(t, 0);

#pragma unroll 1
    for (; t < ntiles; t += stride) {
        __syncthreads();   // drains STAGE(cur); prev tile's buf reads all done
        const int tn = t + stride;
        if (tn < ntiles) STAGE(tn, cur ^ 1);   // in flight under this tile's compute

        // alpha: sequential f32x4 (L2), shuffled on the fly below
        const f32x4 alp = *(const f32x4*)(alpha4 + (size_t)(t * 64 + eg * 32 + (lane & 31)) * 4);

        // A fragments: h-invariant, read once, held (32 VGPR)
        s16x8 af[2][4];
#pragma unroll
        for (int eb = 0; eb < 2; eb++) {
            const int rr = eg * 32 + eb * 16 + (lane & 15);
#pragma unroll
            for (int ks = 0; ks < 4; ks++) {
                const int byte = rr * 256 + ((ks * 64 + (lane >> 4) * 16) ^ ((rr & 15) << 4));
                af[eb][ks] = *(const s16x8*)((const char*)Asm[cur] + byte);
            }
        }

        f32x4 fin[2];
        fin[0] = zero; fin[1] = zero;

#pragma unroll
        for (int h = 0; h < 4; h++) {
            s16x8 bfr[4];
#pragma unroll
            for (int ks = 0; ks < 4; ks++) {
                const int byte = icol * 1024 +
                    ((h * 256 + ks * 64 + (lane >> 4) * 16) ^ ((icol & 15) << 4));
                bfr[ks] = *(const s16x8*)((const char*)Bsm + byte);
            }
#pragma unroll
            for (int eb = 0; eb < 2; eb++) {
                f32x4 a = __builtin_amdgcn_mfma_f32_16x16x32_bf16(af[eb][0], bfr[0], zero, 0, 0, 0);
#pragma unroll
                for (int ks = 1; ks < 4; ks++)
                    a = __builtin_amdgcn_mfma_f32_16x16x32_bf16(af[eb][ks], bfr[ks], a, 0, 0, 0);
                f32x4 av;
#pragma unroll
                for (int r = 0; r < 4; r++)
                    av[r] = __shfl(alp[h], eb * 16 + (lane >> 4) * 4 + r, 64);
                fin[eb] += av * a;
            }
        }
        // epilogue: + bias + residual
#pragma unroll
        for (int eb = 0; eb < 2; eb++) {
#pragma unroll
            for (int r = 0; r < 4; r++) {
                const int e = t * 64 + eg * 32 + eb * 16 + (lane >> 4) * 4 + r;
                const size_t off = (size_t)e * 128 + icol;
                out[off] = fin[eb][r] + bias_r + bf2f(xbf[off]);
            }
        }
        cur ^= 1;
    }
}

extern "C" void kernel_launch(void* const* d_in, const int* in_sizes, int n_in,
                              void* d_out, int out_size, void* d_ws, size_t ws_size,
                              hipStream_t stream) {
    const float* x      = (const float*)d_in[0];
    const int*   ei_raw = (const int*)d_in[1];
    const float* att    = (const float*)d_in[2];
    const float* W      = (const float*)d_in[3];
    const float* b      = (const float*)d_in[4];
    float* out = (float*)d_out;

    char* ws = (char*)d_ws;
    float*    uv      = (float*)(ws);                     // N*8 f32   = 12.8 MB
    float*    p       = (float*)(ws + 12800000);          // E*4 f32   =  6.4 MB
    float*    denom   = (float*)(ws + 19200000);          // N*4 f32   =  6.4 MB
    float*    alpha4  = (float*)(ws + 25600000);          // E*4 f32   =  6.4 MB
    ushort_t* wbf     = (ushort_t*)(ws + 32000000);       // 128 KB
    int*      flag    = (int*)(ws + 32200000);            // 4 B
    int*      ei32    = (int*)(ws + 32200064);            // 3.2 MB
    ushort_t* xbf     = (ushort_t*)(ws + 35400192);       // N*128 bf16 = 102.4 MB

    hipMemsetAsync(denom, 0, (size_t)NN * 4 * sizeof(float), stream);
    k_detect<<<1, 64, 0, stream>>>(ei_raw, flag);
    k_cvt_idx<<<2 * NE / 256, 256, 0, stream>>>(ei_raw, flag, ei32);
    k_wcvt<<<256, 256, 0, stream>>>(W, wbf);
    k_uv_cvt<<<2048, 256, 0, stream>>>(x, att, xbf, uv);
    k_edge<<<(NE + 255) / 256, 256, 0, stream>>>(ei32, uv, p, denom);
    k_alpha<<<(NE + 255) / 256, 256, 0, stream>>>(ei32, p, denom, alpha4);
    k_gemm<<<256, 1024, 0, stream>>>(xbf, ei32, alpha4, wbf, b, out);
}